// Round 11
// baseline (351.490 us; speedup 1.0000x reference)
//
#include <hip/hip_runtime.h>
#include <math.h>

#define TS 256
#define BB 1024
#define NQ 8
#define INDIM 128
#define CATDIM 136

__device__ __forceinline__ float dpp_xor1(float v) {
    return __int_as_float(__builtin_amdgcn_mov_dpp(__float_as_int(v), 0xB1, 0xF, 0xF, true));
}
__device__ __forceinline__ float dpp_xor2(float v) {
    return __int_as_float(__builtin_amdgcn_mov_dpp(__float_as_int(v), 0x4E, 0xF, 0xF, true));
}
__device__ __forceinline__ float dpp_xor8(float v) {   // row_ror:8 within 16 = lane^8
    return __int_as_float(__builtin_amdgcn_mov_dpp(__float_as_int(v), 0x128, 0xF, 0xF, true));
}
__device__ __forceinline__ float swz_xor16(float v) {  // ds_swizzle BitMode xor 16
    return __int_as_float(__builtin_amdgcn_ds_swizzle(__float_as_int(v), 0x401F));
}

// ============ Kernel 1: xproj[b][t][g*8+q] = x[t][b]·W_g[q][:128] + bias_g[q] ============
// Grid split 4x over t for occupancy: block = (b, tseg).
__launch_bounds__(256)
__global__ void qlstm_xproj(const float* __restrict__ x,
    const float* __restrict__ Wf, const float* __restrict__ bf,
    const float* __restrict__ Wi, const float* __restrict__ bi,
    const float* __restrict__ Wg, const float* __restrict__ bg,
    const float* __restrict__ Wo, const float* __restrict__ bo,
    float* __restrict__ xproj)
{
    const int b = blockIdx.x >> 2;
    const int tseg = blockIdx.x & 3;
    const int wv = threadIdx.x >> 6;
    const int lane = threadIdx.x & 63;
    const int q = lane >> 3;
    const int kg = lane & 7;

    const float* Ws[4] = { Wf, Wi, Wg, Wo };
    const float* bs[4] = { bf, bi, bg, bo };
    float4 wfrag[4][4];
    float bias_w[4];
    #pragma unroll
    for (int g = 0; g < 4; ++g) {
        const float* Wq = Ws[g] + q * CATDIM + kg * 16;
        #pragma unroll
        for (int c4 = 0; c4 < 4; ++c4) wfrag[g][c4] = *(const float4*)(Wq + c4 * 4);
        bias_w[g] = bs[g][q];
    }

    const int t0 = tseg * 64 + wv;
    #pragma unroll 4
    for (int i = 0; i < 16; ++i) {
        int t = t0 + i * 4;
        const float* xr = x + ((size_t)t * BB + b) * INDIM + kg * 16;
        float4 x0 = *(const float4*)(xr);
        float4 x1 = *(const float4*)(xr + 4);
        float4 x2 = *(const float4*)(xr + 8);
        float4 x3 = *(const float4*)(xr + 12);
        float* outrow = xproj + ((size_t)b * TS + t) * 32;
        #pragma unroll
        for (int g = 0; g < 4; ++g) {
            float p =
                x0.x*wfrag[g][0].x + x0.y*wfrag[g][0].y + x0.z*wfrag[g][0].z + x0.w*wfrag[g][0].w +
                x1.x*wfrag[g][1].x + x1.y*wfrag[g][1].y + x1.z*wfrag[g][1].z + x1.w*wfrag[g][1].w +
                x2.x*wfrag[g][2].x + x2.y*wfrag[g][2].y + x2.z*wfrag[g][2].z + x2.w*wfrag[g][2].w +
                x3.x*wfrag[g][3].x + x3.y*wfrag[g][3].y + x3.z*wfrag[g][3].z + x3.w*wfrag[g][3].w;
            p += dpp_xor1(p);
            p += dpp_xor2(p);
            p += __shfl_xor(p, 4, 64);
            if (kg == 0) outrow[g * 8 + q] = p + bias_w[g];
        }
    }
}

// ============ Kernel 2: q-split transfer-matrix, 2 elements per lane ============
// Lane = (el2, g, q). Block = 1 wave = 4 elements (el2 halves x {A,B}).
// Phases interleaved A/B for ILP. Wire share via stride-5 padded LDS
// (conflict-free); h via broadcast float4; acts via dpp_xor8 + ds_swizzle.
// No barriers (single wave; DS in-order).
__launch_bounds__(64, 1)
__global__ void qlstm_q2(const float* __restrict__ xproj,
    const float* __restrict__ Wf, const float* __restrict__ Pf,
    const float* __restrict__ Wi, const float* __restrict__ Pi,
    const float* __restrict__ Wg, const float* __restrict__ Pg,
    const float* __restrict__ Wo, const float* __restrict__ Po,
    float* __restrict__ out, float* __restrict__ hst, float* __restrict__ cst)
{
    const int lane = threadIdx.x;
    const int q = lane & 7;
    const int g = (lane >> 3) & 3;
    const int el2 = lane >> 5;
    const int bA = blockIdx.x * 4 + el2 * 2;
    const int bB = bA + 1;

    __shared__ float wlds[640];                       // [AB][64 lanes x stride5]
    __shared__ __align__(16) float hlds[32];          // [el2][AB][8]

    const float* W; const float* P;
    if (g == 0)      { W = Wf; P = Pf; }
    else if (g == 1) { W = Wi; P = Pi; }
    else if (g == 2) { W = Wg; P = Pg; }
    else             { W = Wo; P = Po; }

    // ---- loop-invariant constants (shared by A and B) ----
    float Cw[8], Sw[8], hsp0[8], cp0c[8];
    #pragma unroll
    for (int w = 0; w < 8; ++w) {
        float s1, c1, s0, c0;
        __sincosf(P[8 + w], &s1, &c1);
        __sincosf(P[w], &s0, &c0);
        Cw[w] = c1; Sw[w] = s1;
        hsp0[w] = 0.5f * s0;
        cp0c[w] = c0;
    }
    float wh[8];
    {
        const float* Wq = W + q * CATDIM + INDIM;
        #pragma unroll
        for (int j = 0; j < 8; ++j) wh[j] = Wq[j];
    }
    const float kk = (g == 2) ? 2.f : -1.f;
    const float Aa = (g == 2) ? 1.f : 0.f;
    const float Bb = (g == 2) ? -1.f : 1.f;

    if (lane < 32) hlds[lane] = 0.f;                  // in-order DS, no barrier

    float cA = 0.f, hvA = 0.f, cB = 0.f, hvB = 0.f;

    const float* xbaseA = xproj + ((size_t)bA * TS) * 32 + (g * 8 + q);
    const float* xbaseB = xproj + ((size_t)bB * TS) * 32 + (g * 8 + q);
    float xbA = xbaseA[0];
    float xbB = xbaseB[0];

    const int wb = 5 * lane;                          // write base (words)
    const int rb = 5 * (lane & 56);                   // read base (group)
    const int hbase = el2 * 16;

    for (int t = 0; t < TS; ++t) {
        // ======== phase 1: angles + sincos (A, B) ========
        float4 hA0 = *(const float4*)&hlds[hbase];
        float4 hA1 = *(const float4*)&hlds[hbase + 4];
        float angA = xbA
            + wh[0]*hA0.x + wh[1]*hA0.y + wh[2]*hA0.z + wh[3]*hA0.w
            + wh[4]*hA1.x + wh[5]*hA1.y + wh[6]*hA1.z + wh[7]*hA1.w;
        float4 hB0 = *(const float4*)&hlds[hbase + 8];
        float4 hB1 = *(const float4*)&hlds[hbase + 12];
        float angB = xbB
            + wh[0]*hB0.x + wh[1]*hB0.y + wh[2]*hB0.z + wh[3]*hB0.w
            + wh[4]*hB1.x + wh[5]*hB1.y + wh[6]*hB1.z + wh[7]*hB1.w;

        float saA, caA, saB, caB;
        __sincosf(angA, &saA, &caA);
        __sincosf(angB, &saB, &caB);

        // prefetch next xb (off critical path)
        {
            int tn = (t + 1 < TS) ? t + 1 : t;
            xbA = xbaseA[(size_t)tn * 32];
            xbB = xbaseB[(size_t)tn * 32];
        }

        // ======== phase 2: publish wires (stride-5, conflict-free) ========
        wlds[wb] = caA;       wlds[wb + 1] = saA;
        wlds[320 + wb] = caB; wlds[320 + wb + 1] = saB;

        // ======== phase 3: read all 8 wires of own group ========
        float cwA[8], swA[8], cwB[8], swB[8];
        #pragma unroll
        for (int w = 0; w < 8; ++w) {
            cwA[w] = wlds[rb + 5 * w];
            swA[w] = wlds[rb + 5 * w + 1];
            cwB[w] = wlds[320 + rb + 5 * w];
            swB[w] = wlds[320 + rb + 5 * w + 1];
        }

        // ======== phase 4: serial transfer chains (A, B interleaved by sched) ========
        float myEA = 0.f, myEB = 0.f;
        {
            float d0A, d1A, zrA, ziA;
            {
                float AmB = cp0c[0] * cwA[0];
                float A_ = 0.5f + 0.5f * AmB;
                d0A = Cw[0] * A_; d1A = -Cw[0] * (1.f - A_);
                zrA = -Sw[0] * (hsp0[0] * cwA[0]);
                ziA = -Sw[0] * (-0.5f * swA[0]);
            }
            float d0B, d1B, zrB, ziB;
            {
                float AmB = cp0c[0] * cwB[0];
                float A_ = 0.5f + 0.5f * AmB;
                d0B = Cw[0] * A_; d1B = -Cw[0] * (1.f - A_);
                zrB = -Sw[0] * (hsp0[0] * cwB[0]);
                ziB = -Sw[0] * (-0.5f * swB[0]);
            }
            #pragma unroll
            for (int w = 1; w < 8; ++w) {
                // --- A ---
                {
                    float gr = hsp0[w] * cwA[w];
                    float gi = -0.5f * swA[w];
                    float AmB = cp0c[w] * cwA[w];
                    float sum = d0A + d1A, dif = d0A - d1A;
                    float p = gr * zrA, qv = gi * ziA;
                    float Ew = fmaf(4.f, p, sum);
                    if (q == w - 1) myEA = Ew;
                    float u  = fmaf(AmB, dif, sum);
                    float u2 = fmaf(-AmB, dif, sum);
                    float t0 = fmaf(2.f, p - qv, 0.5f * u);
                    float t1 = fmaf(2.f, p + qv, 0.5f * u2);
                    float nzr = -Sw[w] * fmaf(gr, sum, zrA);
                    float nzi = -Sw[w] * fmaf(AmB, ziA, gi * dif);
                    d0A = Cw[w] * t0; d1A = -Cw[w] * t1;
                    zrA = nzr; ziA = nzi;
                }
                // --- B ---
                {
                    float gr = hsp0[w] * cwB[w];
                    float gi = -0.5f * swB[w];
                    float AmB = cp0c[w] * cwB[w];
                    float sum = d0B + d1B, dif = d0B - d1B;
                    float p = gr * zrB, qv = gi * ziB;
                    float Ew = fmaf(4.f, p, sum);
                    if (q == w - 1) myEB = Ew;
                    float u  = fmaf(AmB, dif, sum);
                    float u2 = fmaf(-AmB, dif, sum);
                    float t0 = fmaf(2.f, p - qv, 0.5f * u);
                    float t1 = fmaf(2.f, p + qv, 0.5f * u2);
                    float nzr = -Sw[w] * fmaf(gr, sum, zrB);
                    float nzi = -Sw[w] * fmaf(AmB, ziB, gi * dif);
                    d0B = Cw[w] * t0; d1B = -Cw[w] * t1;
                    zrB = nzr; ziB = nzi;
                }
            }
            if (q == 7) {
                myEA = (d0A + d1A) + 2.f * zrA;
                myEB = (d0B + d1B) + 2.f * zrB;
            }
        }

        // ======== phase 5: activations, gate gather, LSTM, publish ========
        float yA = __expf(kk * myEA);
        float aA = fmaf(Aa, yA, Bb) / (yA + 1.f);
        float yB = __expf(kk * myEB);
        float aB = fmaf(Aa, yB, Bb) / (yB + 1.f);

        // gather 4 gates' activations for own qubit (verified R10)
        float a8A = dpp_xor8(aA);
        float pAxA = (g & 1) ? a8A : aA;
        float pAyA = (g & 1) ? aA : a8A;
        float pBxA = swz_xor16(pAxA);
        float pByA = swz_xor16(pAyA);
        float a8B = dpp_xor8(aB);
        float pAxB = (g & 1) ? a8B : aB;
        float pAyB = (g & 1) ? aB : a8B;
        float pBxB = swz_xor16(pAxB);
        float pByB = swz_xor16(pAyB);

        bool glo = (g & 2) == 0;
        float fvA = glo ? pAxA : pBxA;
        float ivA = glo ? pAyA : pByA;
        float gvA = glo ? pBxA : pAxA;
        float ovA = glo ? pByA : pAyA;
        float fvB = glo ? pAxB : pBxB;
        float ivB = glo ? pAyB : pByB;
        float gvB = glo ? pBxB : pAxB;
        float ovB = glo ? pByB : pAyB;

        cA = fmaf(fvA, cA, ivA * gvA);
        float e2A = __expf(2.f * cA);
        hvA = ovA * ((e2A - 1.f) / (e2A + 1.f));
        cB = fmaf(fvB, cB, ivB * gvB);
        float e2B = __expf(2.f * cB);
        hvB = ovB * ((e2B - 1.f) / (e2B + 1.f));

        if ((lane & 24) == 0) {
            hlds[hbase + q] = hvA;
            hlds[hbase + 8 + q] = hvB;
            out[((size_t)t * BB + bA) * NQ + q] = hvA;
            out[((size_t)t * BB + bB) * NQ + q] = hvB;
        }
    }

    if ((lane & 24) == 0) {
        hst[bA * NQ + q] = hvA;
        cst[bA * NQ + q] = cA;
        hst[bB * NQ + q] = hvB;
        cst[bB * NQ + q] = cB;
    }
}

extern "C" void kernel_launch(void* const* d_in, const int* in_sizes, int n_in,
                              void* d_out, int out_size, void* d_ws, size_t ws_size,
                              hipStream_t stream) {
    const float* x  = (const float*)d_in[0];
    const float* Wf = (const float*)d_in[1];
    const float* bf = (const float*)d_in[2];
    const float* Pf = (const float*)d_in[3];
    const float* Wi = (const float*)d_in[4];
    const float* bi = (const float*)d_in[5];
    const float* Pi = (const float*)d_in[6];
    const float* Wg = (const float*)d_in[7];
    const float* bg = (const float*)d_in[8];
    const float* Pg = (const float*)d_in[9];
    const float* Wo = (const float*)d_in[10];
    const float* bo = (const float*)d_in[11];
    const float* Po = (const float*)d_in[12];

    float* out = (float*)d_out;
    float* hst = out + (size_t)TS * BB * NQ;
    float* cst = hst + (size_t)BB * NQ;
    float* xproj = (float*)d_ws;             // TS*BB*32 floats = 33.5 MB scratch

    qlstm_xproj<<<BB * 4, 256, 0, stream>>>(x, Wf, bf, Wi, bi, Wg, bg, Wo, bo, xproj);
    qlstm_q2<<<BB / 4, 64, 0, stream>>>(xproj, Wf, Pf, Wi, Pi, Wg, Pg, Wo, Po,
                                        out, hst, cst);
}

// Round 12
// 242.831 us; speedup vs baseline: 1.4475x; 1.4475x over previous
//
#include <hip/hip_runtime.h>
#include <math.h>

#define TS 256
#define BB 1024
#define NQ 8
#define INDIM 128
#define CATDIM 136

typedef float v2f __attribute__((ext_vector_type(2)));

__device__ __forceinline__ float dpp_xor1(float v) {
    return __int_as_float(__builtin_amdgcn_mov_dpp(__float_as_int(v), 0xB1, 0xF, 0xF, true));
}
__device__ __forceinline__ float dpp_xor2(float v) {
    return __int_as_float(__builtin_amdgcn_mov_dpp(__float_as_int(v), 0x4E, 0xF, 0xF, true));
}
__device__ __forceinline__ float dpp_xor8(float v) {   // row_ror:8 within 16 = lane^8
    return __int_as_float(__builtin_amdgcn_mov_dpp(__float_as_int(v), 0x128, 0xF, 0xF, true));
}
__device__ __forceinline__ float swz_xor4(float v) {   // ds_swizzle BitMode xor 4
    return __int_as_float(__builtin_amdgcn_ds_swizzle(__float_as_int(v), 0x101F));
}
__device__ __forceinline__ float swz_xor16(float v) {  // ds_swizzle BitMode xor 16
    return __int_as_float(__builtin_amdgcn_ds_swizzle(__float_as_int(v), 0x401F));
}
__device__ __forceinline__ v2f mk2(float x, float y) { v2f r; r.x = x; r.y = y; return r; }
__device__ __forceinline__ v2f pk_mul(v2f a, v2f b) {
    v2f d; asm("v_pk_mul_f32 %0, %1, %2" : "=v"(d) : "v"(a), "v"(b)); return d;
}
__device__ __forceinline__ v2f pk_fma(v2f a, v2f b, v2f c) {
    v2f d; asm("v_pk_fma_f32 %0, %1, %2, %3" : "=v"(d) : "v"(a), "v"(b), "v"(c)); return d;
}

// ============ Kernel 1: xproj[b][t][g*8+q] = x[t][b]·W_g[q][:128] + bias_g[q] ============
// 1024 blocks; wave wv handles t = wv+4i with 1-iter-ahead register prefetch.
__launch_bounds__(256)
__global__ void qlstm_xproj(const float* __restrict__ x,
    const float* __restrict__ Wf, const float* __restrict__ bf,
    const float* __restrict__ Wi, const float* __restrict__ bi,
    const float* __restrict__ Wg, const float* __restrict__ bg,
    const float* __restrict__ Wo, const float* __restrict__ bo,
    float* __restrict__ xproj)
{
    const int b = blockIdx.x;
    const int wv = threadIdx.x >> 6;
    const int lane = threadIdx.x & 63;
    const int q = lane >> 3;
    const int kg = lane & 7;

    const float* Ws[4] = { Wf, Wi, Wg, Wo };
    const float* bs[4] = { bf, bi, bg, bo };
    float4 wfrag[4][4];
    float bias_w[4];
    #pragma unroll
    for (int g = 0; g < 4; ++g) {
        const float* Wq = Ws[g] + q * CATDIM + kg * 16;
        #pragma unroll
        for (int c4 = 0; c4 < 4; ++c4) wfrag[g][c4] = *(const float4*)(Wq + c4 * 4);
        bias_w[g] = bs[g][q];
    }

    // preload row for t = wv
    float4 xv[4];
    {
        const float* xr = x + ((size_t)wv * BB + b) * INDIM + kg * 16;
        #pragma unroll
        for (int c4 = 0; c4 < 4; ++c4) xv[c4] = *(const float4*)(xr + c4 * 4);
    }

    #pragma unroll 2
    for (int i = 0; i < 64; ++i) {
        const int t = wv + i * 4;
        // prefetch next row
        float4 xn[4];
        {
            int t2 = (i < 63) ? t + 4 : t;
            const float* xr = x + ((size_t)t2 * BB + b) * INDIM + kg * 16;
            #pragma unroll
            for (int c4 = 0; c4 < 4; ++c4) xn[c4] = *(const float4*)(xr + c4 * 4);
        }
        float* outrow = xproj + ((size_t)b * TS + t) * 32;
        #pragma unroll
        for (int g = 0; g < 4; ++g) {
            float p =
                xv[0].x*wfrag[g][0].x + xv[0].y*wfrag[g][0].y + xv[0].z*wfrag[g][0].z + xv[0].w*wfrag[g][0].w +
                xv[1].x*wfrag[g][1].x + xv[1].y*wfrag[g][1].y + xv[1].z*wfrag[g][1].z + xv[1].w*wfrag[g][1].w +
                xv[2].x*wfrag[g][2].x + xv[2].y*wfrag[g][2].y + xv[2].z*wfrag[g][2].z + xv[2].w*wfrag[g][2].w +
                xv[3].x*wfrag[g][3].x + xv[3].y*wfrag[g][3].y + xv[3].z*wfrag[g][3].z + xv[3].w*wfrag[g][3].w;
            p += dpp_xor1(p);
            p += dpp_xor2(p);
            p += __shfl_xor(p, 4, 64);
            if (kg == 0) outrow[g * 8 + q] = p + bias_w[g];
        }
        xv[0] = xn[0]; xv[1] = xn[1]; xv[2] = xn[2]; xv[3] = xn[3];
    }
}

// ============ Kernel 2: zero-LDS transfer-matrix recurrence ============
// Lane = (el2, g, q); block = 1 wave = 2 elements; 512 waves total.
// Each lane: all-8 angle dots (h gathered in registers via butterfly, with the
// butterfly's q^i slot-permutation folded into the weight load addresses),
// 8 local sincos, the full verified transfer chain, own-q activation; the 4
// gates' activations gathered via dpp_xor8 + ds_swizzle xor16 (proven R10/R11).
// NO LDS, NO barriers; only 6 ds_swizzles per step.
__launch_bounds__(64, 1)
__global__ void qlstm_w(const float* __restrict__ xproj,
    const float* __restrict__ Wf, const float* __restrict__ Pf,
    const float* __restrict__ Wi, const float* __restrict__ Pi,
    const float* __restrict__ Wg, const float* __restrict__ Pg,
    const float* __restrict__ Wo, const float* __restrict__ Po,
    float* __restrict__ out, float* __restrict__ hst, float* __restrict__ cst)
{
    const int lane = threadIdx.x;
    const int q = lane & 7;
    const int g = (lane >> 3) & 3;
    const int el2 = lane >> 5;
    const int b = blockIdx.x * 2 + el2;

    const float* W; const float* P;
    if (g == 0)      { W = Wf; P = Pf; }
    else if (g == 1) { W = Wi; P = Pi; }
    else if (g == 2) { W = Wg; P = Pg; }
    else             { W = Wo; P = Po; }

    // ---- per-wire trig constants ----
    float Cw[8], Sw[8], hsp0[8], cp0c[8];
    #pragma unroll
    for (int w = 0; w < 8; ++w) {
        float s1, c1, s0, c0;
        __sincosf(P[8 + w], &s1, &c1);
        __sincosf(P[w], &s0, &c0);
        Cw[w] = c1; Sw[w] = s1;
        hsp0[w] = 0.5f * s0;
        cp0c[w] = c0;
    }

    // ---- h-weights for all 8 qubits, with butterfly slot-permutation folded:
    //      slot i after the allgather holds h[q^i], so load wh_j[q^i] at slot i.
    v2f whp[8][4];
    #pragma unroll
    for (int j = 0; j < 8; ++j) {
        const float* Wj = W + j * CATDIM + INDIM;
        #pragma unroll
        for (int p2 = 0; p2 < 4; ++p2)
            whp[j][p2] = mk2(Wj[q ^ (2 * p2)], Wj[q ^ (2 * p2 + 1)]);
    }

    // activation constants: act = (Aa*y + Bb)/(y+1), y = exp(kk*E)
    const float kk = (g == 2) ? 2.f : -1.f;
    const float Aa = (g == 2) ? 1.f : 0.f;
    const float Bb = (g == 2) ? -1.f : 1.f;

    // ---- state ----
    float s0h = 0.f, s1h = 0.f, s2h = 0.f, s3h = 0.f;
    float s4h = 0.f, s5h = 0.f, s6h = 0.f, s7h = 0.f;   // slot i = h[q^i]
    float c_own = 0.f, hv = 0.f;

    const float* xbase = xproj + ((size_t)b * TS) * 32 + g * 8;
    float4 xv0 = *(const float4*)(xbase);
    float4 xv1 = *(const float4*)(xbase + 4);

    for (int t = 0; t < TS; ++t) {
        // ---- all-8 angle dots + sincos (local, no exchange) ----
        v2f hp0 = mk2(s0h, s1h), hp1 = mk2(s2h, s3h);
        v2f hp2 = mk2(s4h, s5h), hp3 = mk2(s6h, s7h);
        float xq[8] = { xv0.x, xv0.y, xv0.z, xv0.w, xv1.x, xv1.y, xv1.z, xv1.w };
        float sa[8], ca[8];
        #pragma unroll
        for (int j = 0; j < 8; ++j) {
            v2f acc = pk_mul(hp0, whp[j][0]);
            acc = pk_fma(hp1, whp[j][1], acc);
            acc = pk_fma(hp2, whp[j][2], acc);
            acc = pk_fma(hp3, whp[j][3], acc);
            float ang = xq[j] + acc.x + acc.y;
            __sincosf(ang, &sa[j], &ca[j]);
        }

        // prefetch next xproj row
        {
            int tn = (t + 1 < TS) ? t + 1 : t;
            xv0 = *(const float4*)(xbase + (size_t)tn * 32);
            xv1 = *(const float4*)(xbase + (size_t)tn * 32 + 4);
        }

        // ---- serial transfer chain (verified R9-R11), selecting own E ----
        float myE = 0.f;
        float d0, d1, zr, zi;
        {
            float AmB = cp0c[0] * ca[0];
            float A_ = 0.5f + 0.5f * AmB;
            d0 = Cw[0] * A_;
            d1 = -Cw[0] * (1.f - A_);
            zr = -Sw[0] * (hsp0[0] * ca[0]);
            zi = -Sw[0] * (-0.5f * sa[0]);
        }
        #pragma unroll
        for (int w = 1; w < 8; ++w) {
            float gr = hsp0[w] * ca[w];
            float gi = -0.5f * sa[w];
            float AmB = cp0c[w] * ca[w];
            float sum = d0 + d1, dif = d0 - d1;
            float p = gr * zr, qv = gi * zi;
            float Ew = fmaf(4.f, p, sum);
            if (q == w - 1) myE = Ew;
            float u  = fmaf(AmB, dif, sum);
            float u2 = fmaf(-AmB, dif, sum);
            float t0 = fmaf(2.f, p - qv, 0.5f * u);
            float t1 = fmaf(2.f, p + qv, 0.5f * u2);
            float nzr = -Sw[w] * fmaf(gr, sum, zr);
            float nzi = -Sw[w] * fmaf(AmB, zi, gi * dif);
            d0 = Cw[w] * t0;
            d1 = -Cw[w] * t1;
            zr = nzr; zi = nzi;
        }
        if (q == 7) myE = (d0 + d1) + 2.f * zr;

        // ---- own activation ----
        float y = __expf(kk * myE);
        float a = fmaf(Aa, y, Bb) / (y + 1.f);

        // ---- gather 4 gates' activations for own qubit (verified R10/R11) ----
        float a8 = dpp_xor8(a);
        float pAx = (g & 1) ? a8 : a;
        float pAy = (g & 1) ? a : a8;
        float pBx = swz_xor16(pAx);
        float pBy = swz_xor16(pAy);
        bool glo = (g & 2) == 0;
        float fv = glo ? pAx : pBx;
        float iv = glo ? pAy : pBy;
        float gv = glo ? pBx : pAx;
        float ov = glo ? pBy : pAy;

        // ---- lane-local LSTM (replicated across g, deterministic) ----
        c_own = fmaf(fv, c_own, iv * gv);
        float e2 = __expf(2.f * c_own);
        hv = ov * ((e2 - 1.f) / (e2 + 1.f));

        if ((lane & 24) == 0)
            out[((size_t)t * BB + b) * NQ + q] = hv;

        // ---- h allgather butterfly: slot i <- h[q^i] ----
        s0h = hv;
        s1h = dpp_xor1(s0h);
        s2h = dpp_xor2(s0h);
        s3h = dpp_xor2(s1h);
        s4h = swz_xor4(s0h);
        s5h = swz_xor4(s1h);
        s6h = swz_xor4(s2h);
        s7h = swz_xor4(s3h);
    }

    if ((lane & 24) == 0) {
        hst[b * NQ + q] = hv;
        cst[b * NQ + q] = c_own;
    }
}

extern "C" void kernel_launch(void* const* d_in, const int* in_sizes, int n_in,
                              void* d_out, int out_size, void* d_ws, size_t ws_size,
                              hipStream_t stream) {
    const float* x  = (const float*)d_in[0];
    const float* Wf = (const float*)d_in[1];
    const float* bf = (const float*)d_in[2];
    const float* Pf = (const float*)d_in[3];
    const float* Wi = (const float*)d_in[4];
    const float* bi = (const float*)d_in[5];
    const float* Pi = (const float*)d_in[6];
    const float* Wg = (const float*)d_in[7];
    const float* bg = (const float*)d_in[8];
    const float* Pg = (const float*)d_in[9];
    const float* Wo = (const float*)d_in[10];
    const float* bo = (const float*)d_in[11];
    const float* Po = (const float*)d_in[12];

    float* out = (float*)d_out;
    float* hst = out + (size_t)TS * BB * NQ;
    float* cst = hst + (size_t)BB * NQ;
    float* xproj = (float*)d_ws;             // TS*BB*32 floats = 33.5 MB scratch

    qlstm_xproj<<<BB, 256, 0, stream>>>(x, Wf, bf, Wi, bi, Wg, bg, Wo, bo, xproj);
    qlstm_w<<<BB / 2, 64, 0, stream>>>(xproj, Wf, Pf, Wi, Pi, Wg, Pg, Wo, Po,
                                       out, hst, cst);
}

// Round 13
// 238.332 us; speedup vs baseline: 1.4748x; 1.0189x over previous
//
#include <hip/hip_runtime.h>
#include <math.h>

#define TS 256
#define BB 1024
#define NQ 8
#define INDIM 128
#define CATDIM 136
#define INV2PI 0.15915494309189535f
#define LOG2E  1.4426950408889634f

typedef float v2f __attribute__((ext_vector_type(2)));

__device__ __forceinline__ float dpp_xor1(float v) {
    return __int_as_float(__builtin_amdgcn_mov_dpp(__float_as_int(v), 0xB1, 0xF, 0xF, true));
}
__device__ __forceinline__ float dpp_xor2(float v) {
    return __int_as_float(__builtin_amdgcn_mov_dpp(__float_as_int(v), 0x4E, 0xF, 0xF, true));
}
__device__ __forceinline__ float dpp_xor8(float v) {   // row_ror:8 within 16-lane row = lane^8
    return __int_as_float(__builtin_amdgcn_mov_dpp(__float_as_int(v), 0x128, 0xF, 0xF, true));
}
__device__ __forceinline__ float swz4(float v)  {      // ds_swizzle xor 4
    return __int_as_float(__builtin_amdgcn_ds_swizzle(__float_as_int(v), 0x101F));
}
__device__ __forceinline__ float swz16(float v) {      // ds_swizzle xor 16
    return __int_as_float(__builtin_amdgcn_ds_swizzle(__float_as_int(v), 0x401F));
}
__device__ __forceinline__ float swz20(float v) {      // ds_swizzle xor 20
    return __int_as_float(__builtin_amdgcn_ds_swizzle(__float_as_int(v), 0x501F));
}
__device__ __forceinline__ float hw_sin(float x) { float r; asm("v_sin_f32 %0, %1" : "=v"(r) : "v"(x)); return r; }
__device__ __forceinline__ float hw_cos(float x) { float r; asm("v_cos_f32 %0, %1" : "=v"(r) : "v"(x)); return r; }
__device__ __forceinline__ float hw_exp(float x) { float r; asm("v_exp_f32 %0, %1" : "=v"(r) : "v"(x)); return r; }
__device__ __forceinline__ float hw_rcp(float x) { float r; asm("v_rcp_f32 %0, %1" : "=v"(r) : "v"(x)); return r; }
__device__ __forceinline__ v2f mk2(float x, float y) { v2f r; r.x = x; r.y = y; return r; }
__device__ __forceinline__ v2f pk_mul(v2f a, v2f b) {
    v2f d; asm("v_pk_mul_f32 %0, %1, %2" : "=v"(d) : "v"(a), "v"(b)); return d;
}
__device__ __forceinline__ v2f pk_fma(v2f a, v2f b, v2f c) {
    v2f d; asm("v_pk_fma_f32 %0, %1, %2, %3" : "=v"(d) : "v"(a), "v"(b), "v"(c)); return d;
}

// ============ Kernel 1: xproj[b][t][g*8+q] = (x[t][b]·W_g[q] + bias) / 2π ============
__launch_bounds__(256)
__global__ void qlstm_xproj(const float* __restrict__ x,
    const float* __restrict__ Wf, const float* __restrict__ bf,
    const float* __restrict__ Wi, const float* __restrict__ bi,
    const float* __restrict__ Wg, const float* __restrict__ bg,
    const float* __restrict__ Wo, const float* __restrict__ bo,
    float* __restrict__ xproj)
{
    const int b = blockIdx.x;
    const int wv = threadIdx.x >> 6;
    const int lane = threadIdx.x & 63;
    const int q = lane >> 3;
    const int kg = lane & 7;

    const float* Ws[4] = { Wf, Wi, Wg, Wo };
    const float* bs[4] = { bf, bi, bg, bo };
    float4 wfrag[4][4];
    float bias_w[4];
    #pragma unroll
    for (int g = 0; g < 4; ++g) {
        const float* Wq = Ws[g] + q * CATDIM + kg * 16;
        #pragma unroll
        for (int c4 = 0; c4 < 4; ++c4) {
            float4 v = *(const float4*)(Wq + c4 * 4);
            v.x *= INV2PI; v.y *= INV2PI; v.z *= INV2PI; v.w *= INV2PI;
            wfrag[g][c4] = v;
        }
        bias_w[g] = bs[g][q] * INV2PI;
    }

    float4 xv[4];
    {
        const float* xr = x + ((size_t)wv * BB + b) * INDIM + kg * 16;
        #pragma unroll
        for (int c4 = 0; c4 < 4; ++c4) xv[c4] = *(const float4*)(xr + c4 * 4);
    }

    #pragma unroll 2
    for (int i = 0; i < 64; ++i) {
        const int t = wv + i * 4;
        float4 xn[4];
        {
            int t2 = (i < 63) ? t + 4 : t;
            const float* xr = x + ((size_t)t2 * BB + b) * INDIM + kg * 16;
            #pragma unroll
            for (int c4 = 0; c4 < 4; ++c4) xn[c4] = *(const float4*)(xr + c4 * 4);
        }
        float* outrow = xproj + ((size_t)b * TS + t) * 32;
        #pragma unroll
        for (int g = 0; g < 4; ++g) {
            float p =
                xv[0].x*wfrag[g][0].x + xv[0].y*wfrag[g][0].y + xv[0].z*wfrag[g][0].z + xv[0].w*wfrag[g][0].w +
                xv[1].x*wfrag[g][1].x + xv[1].y*wfrag[g][1].y + xv[1].z*wfrag[g][1].z + xv[1].w*wfrag[g][1].w +
                xv[2].x*wfrag[g][2].x + xv[2].y*wfrag[g][2].y + xv[2].z*wfrag[g][2].z + xv[2].w*wfrag[g][2].w +
                xv[3].x*wfrag[g][3].x + xv[3].y*wfrag[g][3].y + xv[3].z*wfrag[g][3].z + xv[3].w*wfrag[g][3].w;
            p += dpp_xor1(p);
            p += dpp_xor2(p);
            p += __shfl_xor(p, 4, 64);
            if (kg == 0) outrow[g * 8 + q] = p + bias_w[g];
        }
        xv[0] = xn[0]; xv[1] = xn[1]; xv[2] = xn[2]; xv[3] = xn[3];
    }
}

// ============ Kernel 2: zero-LDS TM recurrence, DPP-butterfly layout ============
// lane = el2*32 + g1*16 + g0*4 + q2*8 + q1*2 + q0  (q bits on DPP masks 1,2,8;
// g bits on swizzle masks 4,16). Angles pre-scaled by 1/2π -> raw v_sin/v_cos.
// kk*log2e folded into E-selection fmas -> raw v_exp. All division via v_rcp.
__launch_bounds__(64, 1)
__global__ void qlstm_v(const float* __restrict__ xproj,
    const float* __restrict__ Wf, const float* __restrict__ Pf,
    const float* __restrict__ Wi, const float* __restrict__ Pi,
    const float* __restrict__ Wg, const float* __restrict__ Pg,
    const float* __restrict__ Wo, const float* __restrict__ Po,
    float* __restrict__ out, float* __restrict__ hst, float* __restrict__ cst)
{
    const int lane = threadIdx.x;
    const int q = (lane & 1) | (lane & 2) | ((lane >> 1) & 4);   // bits 0,1,3
    const int g = ((lane >> 2) & 1) | ((lane >> 3) & 2);         // bits 2,4
    const int el2 = lane >> 5;
    const int b = blockIdx.x * 2 + el2;

    const float* W; const float* P;
    if (g == 0)      { W = Wf; P = Pf; }
    else if (g == 1) { W = Wi; P = Pi; }
    else if (g == 2) { W = Wg; P = Pg; }
    else             { W = Wo; P = Po; }

    // ---- per-wire trig constants ----
    float Chw[8], nSw[8], hsp0[8], cp0c[8];
    #pragma unroll
    for (int w = 0; w < 8; ++w) {
        float s1, c1, s0, c0;
        __sincosf(P[8 + w], &s1, &c1);
        __sincosf(P[w], &s0, &c0);
        Chw[w] = 0.5f * c1;
        nSw[w] = -s1;
        hsp0[w] = 0.5f * s0;
        cp0c[w] = c0;
    }

    // ---- h-weights (1/2π-scaled), butterfly slot-permutation folded ----
    v2f whp[8][4];
    #pragma unroll
    for (int j = 0; j < 8; ++j) {
        const float* Wj = W + j * CATDIM + INDIM;
        #pragma unroll
        for (int p2 = 0; p2 < 4; ++p2)
            whp[j][p2] = mk2(INV2PI * Wj[q ^ (2 * p2)], INV2PI * Wj[q ^ (2 * p2 + 1)]);
    }

    // ---- activation constants; kk*log2e folded into E-select coefficients ----
    const float kk = (g == 2) ? 2.f : -1.f;
    const float kl = kk * LOG2E;
    const float Aa = (g == 2) ? 1.f : 0.f;
    const float Bb = (g == 2) ? -1.f : 1.f;
    float sel[8];
    #pragma unroll
    for (int i = 0; i < 8; ++i) sel[i] = (q == i) ? kl : 0.f;

    // ---- state: slot i = h[q^i]; lane-local cell ----
    float s0h = 0.f, s1h = 0.f, s2h = 0.f, s3h = 0.f;
    float s4h = 0.f, s5h = 0.f, s6h = 0.f, s7h = 0.f;
    float c_own = 0.f, hv = 0.f;

    const float* xbase = xproj + ((size_t)b * TS) * 32 + g * 8;
    float4 xv0 = *(const float4*)(xbase);
    float4 xv1 = *(const float4*)(xbase + 4);

    for (int t = 0; t < TS; ++t) {
        // ---- 8 angle dots (pre-scaled) + hw sincos ----
        v2f hp0 = mk2(s0h, s1h), hp1 = mk2(s2h, s3h);
        v2f hp2 = mk2(s4h, s5h), hp3 = mk2(s6h, s7h);
        float xq[8] = { xv0.x, xv0.y, xv0.z, xv0.w, xv1.x, xv1.y, xv1.z, xv1.w };
        float sa[8], ca[8];
        #pragma unroll
        for (int j = 0; j < 8; ++j) {
            v2f acc = pk_fma(hp0, whp[j][0], mk2(xq[j], 0.f));
            acc = pk_fma(hp1, whp[j][1], acc);
            acc = pk_fma(hp2, whp[j][2], acc);
            acc = pk_fma(hp3, whp[j][3], acc);
            float ang = acc.x + acc.y;
            sa[j] = hw_sin(ang);
            ca[j] = hw_cos(ang);
        }

        // prefetch next xproj row
        {
            int tn = (t + 1 < TS) ? t + 1 : t;
            xv0 = *(const float4*)(xbase + (size_t)tn * 32);
            xv1 = *(const float4*)(xbase + (size_t)tn * 32 + 4);
        }

        // ---- serial transfer chain, E accumulated via sel-fma (kE = kk*log2e*E) ----
        float kE = 0.f;
        float d0, d1, zr, zi;
        {
            float AmB = cp0c[0] * ca[0];
            float gr = hsp0[0] * ca[0];
            float gi = -0.5f * sa[0];
            d0 = Chw[0] * (1.f + AmB);
            d1 = -(Chw[0] * (1.f - AmB));
            zr = nSw[0] * gr;
            zi = nSw[0] * gi;
        }
        #pragma unroll
        for (int w = 1; w < 8; ++w) {
            float gr = hsp0[w] * ca[w];
            float gi = -0.5f * sa[w];
            float AmB = cp0c[w] * ca[w];
            float sum = d0 + d1, dif = d0 - d1;
            float p = gr * zr, qv = gi * zi;
            float Ew = fmaf(4.f, p, sum);
            kE = fmaf(sel[w - 1], Ew, kE);
            float ad = AmB * dif;
            float e1 = sum + ad, e3 = sum - ad;
            float e2 = p - qv, e4 = p + qv;
            float T0 = fmaf(4.f, e2, e1);
            float T1 = fmaf(4.f, e4, e3);
            float f1 = fmaf(gr, sum, zr);
            float f2 = gi * dif;
            float f3 = fmaf(AmB, zi, f2);
            d0 = Chw[w] * T0;
            d1 = -(Chw[w] * T1);
            zr = nSw[w] * f1;
            zi = nSw[w] * f3;
        }
        {
            float E7 = (d0 + d1) + 2.f * zr;
            kE = fmaf(sel[7], E7, kE);
        }

        // ---- own activation: act = (Aa*y + Bb) * rcp(y + 1), y = 2^kE ----
        float y = hw_exp(kE);
        float a = fmaf(Aa, y, Bb) * hw_rcp(y + 1.f);

        // ---- gather 4 gates (one DS level: masks 4, 16, 20 in parallel) ----
        float b4 = swz4(a);
        float b16 = swz16(a);
        float b20 = swz20(a);
        bool g1b = (g & 2) != 0;
        bool g0b = (g & 1) != 0;
        float e0 = g1b ? b16 : a;     // act[g0]
        float e1s = g1b ? b20 : b4;   // act[g0^1]
        float e2s = g1b ? a : b16;    // act[2+g0]
        float e3s = g1b ? b4 : b20;   // act[2+(g0^1)]
        float fv = g0b ? e1s : e0;
        float iv = g0b ? e0 : e1s;
        float gv = g0b ? e3s : e2s;
        float ov = g0b ? e2s : e3s;

        // ---- lane-local LSTM ----
        c_own = fmaf(fv, c_own, iv * gv);
        float e2c = hw_exp(c_own * (2.f * LOG2E));
        hv = ov * ((e2c - 1.f) * hw_rcp(e2c + 1.f));

        if ((lane & 0x14) == 0)
            out[((size_t)t * BB + b) * NQ + q] = hv;

        // ---- h allgather butterfly: ALL DPP (masks 1,2,8) ----
        s0h = hv;
        s1h = dpp_xor1(s0h);
        s2h = dpp_xor2(s0h);
        s3h = dpp_xor2(s1h);
        s4h = dpp_xor8(s0h);
        s5h = dpp_xor8(s1h);
        s6h = dpp_xor8(s2h);
        s7h = dpp_xor8(s3h);
    }

    if ((lane & 0x14) == 0) {
        hst[b * NQ + q] = hv;
        cst[b * NQ + q] = c_own;
    }
}

extern "C" void kernel_launch(void* const* d_in, const int* in_sizes, int n_in,
                              void* d_out, int out_size, void* d_ws, size_t ws_size,
                              hipStream_t stream) {
    const float* x  = (const float*)d_in[0];
    const float* Wf = (const float*)d_in[1];
    const float* bf = (const float*)d_in[2];
    const float* Pf = (const float*)d_in[3];
    const float* Wi = (const float*)d_in[4];
    const float* bi = (const float*)d_in[5];
    const float* Pi = (const float*)d_in[6];
    const float* Wg = (const float*)d_in[7];
    const float* bg = (const float*)d_in[8];
    const float* Pg = (const float*)d_in[9];
    const float* Wo = (const float*)d_in[10];
    const float* bo = (const float*)d_in[11];
    const float* Po = (const float*)d_in[12];

    float* out = (float*)d_out;
    float* hst = out + (size_t)TS * BB * NQ;
    float* cst = hst + (size_t)BB * NQ;
    float* xproj = (float*)d_ws;             // TS*BB*32 floats = 33.5 MB scratch

    qlstm_xproj<<<BB, 256, 0, stream>>>(x, Wf, bf, Wi, bi, Wg, bg, Wo, bo, xproj);
    qlstm_v<<<BB / 2, 64, 0, stream>>>(xproj, Wf, Pf, Wi, Pi, Wg, Pg, Wo, Po,
                                       out, hst, cst);
}

// Round 14
// 236.374 us; speedup vs baseline: 1.4870x; 1.0083x over previous
//
#include <hip/hip_runtime.h>
#include <math.h>

#define TS 256
#define BB 1024
#define NQ 8
#define INDIM 128
#define CATDIM 136
#define INV2PI 0.15915494309189535f
#define LOG2E  1.4426950408889634f

typedef float v2f __attribute__((ext_vector_type(2)));

__device__ __forceinline__ float dpp_xor1(float v) {
    return __int_as_float(__builtin_amdgcn_mov_dpp(__float_as_int(v), 0xB1, 0xF, 0xF, true));
}
__device__ __forceinline__ float dpp_xor2(float v) {
    return __int_as_float(__builtin_amdgcn_mov_dpp(__float_as_int(v), 0x4E, 0xF, 0xF, true));
}
__device__ __forceinline__ float dpp_xor8(float v) {   // row_ror:8 within 16-lane row = lane^8
    return __int_as_float(__builtin_amdgcn_mov_dpp(__float_as_int(v), 0x128, 0xF, 0xF, true));
}
__device__ __forceinline__ float swz4(float v)  {      // ds_swizzle xor 4
    return __int_as_float(__builtin_amdgcn_ds_swizzle(__float_as_int(v), 0x101F));
}
__device__ __forceinline__ float swz16(float v) {      // ds_swizzle xor 16
    return __int_as_float(__builtin_amdgcn_ds_swizzle(__float_as_int(v), 0x401F));
}
__device__ __forceinline__ float swz20(float v) {      // ds_swizzle xor 20
    return __int_as_float(__builtin_amdgcn_ds_swizzle(__float_as_int(v), 0x501F));
}
__device__ __forceinline__ float bperm(int addr, float v) {
    return __int_as_float(__builtin_amdgcn_ds_bpermute(addr, __float_as_int(v)));
}
__device__ __forceinline__ float hw_sin(float x) { float r; asm("v_sin_f32 %0, %1" : "=v"(r) : "v"(x)); return r; }
__device__ __forceinline__ float hw_cos(float x) { float r; asm("v_cos_f32 %0, %1" : "=v"(r) : "v"(x)); return r; }
__device__ __forceinline__ float hw_exp(float x) { float r; asm("v_exp_f32 %0, %1" : "=v"(r) : "v"(x)); return r; }
__device__ __forceinline__ float hw_rcp(float x) { float r; asm("v_rcp_f32 %0, %1" : "=v"(r) : "v"(x)); return r; }
__device__ __forceinline__ v2f mk2(float x, float y) { v2f r; r.x = x; r.y = y; return r; }
__device__ __forceinline__ v2f pk_mul(v2f a, v2f b) {
    v2f d; asm("v_pk_mul_f32 %0, %1, %2" : "=v"(d) : "v"(a), "v"(b)); return d;
}
__device__ __forceinline__ v2f pk_fma(v2f a, v2f b, v2f c) {
    v2f d; asm("v_pk_fma_f32 %0, %1, %2, %3" : "=v"(d) : "v"(a), "v"(b), "v"(c)); return d;
}

// ============ Single fused kernel: x-proj + TM recurrence ============
// lane = el2*32 + l4*16 + l3*8 + l2*4 + l1*2 + l0
//   q = 4*l0 + 2*l1 + l3  (chosen so the x-dot butterfly reduce lands row=q)
//   g = l2 + 2*l4
// Per step: each lane computes 8 partial x-dots over its own 16-wide k-chunk
// (chunk id = q), butterfly-reduces (DPP masks 1,2,8) so it holds row q's full
// x-dot; adds bias + own-row h-dot (h slots allgathered via DPP butterfly,
// weight order address-folded); ONE sincos; the 8 wires' (sa,ca) gathered in
// absolute order via ds_bpermute (addresses precomputed); then the verified
// transfer chain (R9-R13), own-E selection, activation, 3-swizzle gate gather,
// lane-local LSTM. Zero LDS, zero barriers, one kernel, no workspace.
__launch_bounds__(64, 1)
__global__ void qlstm_f(const float* __restrict__ x,
    const float* __restrict__ Wf, const float* __restrict__ bf, const float* __restrict__ Pf,
    const float* __restrict__ Wi, const float* __restrict__ bi, const float* __restrict__ Pi,
    const float* __restrict__ Wg, const float* __restrict__ bg, const float* __restrict__ Pg,
    const float* __restrict__ Wo, const float* __restrict__ bo, const float* __restrict__ Po,
    float* __restrict__ out, float* __restrict__ hst, float* __restrict__ cst)
{
    const int lane = threadIdx.x;
    const int l0 = lane & 1, l1 = (lane >> 1) & 1, l3 = (lane >> 3) & 1;
    const int q = 4 * l0 + 2 * l1 + l3;
    const int g = ((lane >> 2) & 1) | ((lane >> 3) & 2);
    const int el2 = lane >> 5;
    const int b = blockIdx.x * 2 + el2;

    const float* W; const float* P; const float* bs;
    if (g == 0)      { W = Wf; P = Pf; bs = bf; }
    else if (g == 1) { W = Wi; P = Pi; bs = bi; }
    else if (g == 2) { W = Wg; P = Pg; bs = bg; }
    else             { W = Wo; P = Po; bs = bo; }

    // ---- per-wire trig constants (wave-uniform) ----
    float Chw[8], nSw[8], hsp0[8], cp0c[8];
    #pragma unroll
    for (int w = 0; w < 8; ++w) {
        float s1, c1, s0, c0;
        __sincosf(P[8 + w], &s1, &c1);
        __sincosf(P[w], &s0, &c0);
        Chw[w] = 0.5f * c1;
        nSw[w] = -s1;
        hsp0[w] = 0.5f * s0;
        cp0c[w] = c0;
    }

    // ---- x-weights: 8 rows x own 16-wide k-chunk (chunk = q), 1/2π-scaled ----
    v2f xw[8][8];
    #pragma unroll
    for (int j = 0; j < 8; ++j) {
        const float* Wj = W + j * CATDIM + 16 * q;
        #pragma unroll
        for (int p2 = 0; p2 < 4; ++p2) {
            float4 v = *(const float4*)(Wj + p2 * 4);
            xw[j][p2*2]   = mk2(INV2PI * v.x, INV2PI * v.y);
            xw[j][p2*2+1] = mk2(INV2PI * v.z, INV2PI * v.w);
        }
    }

    // ---- own-row h-weights, butterfly slot order folded (slot o = h[q^o]) ----
    v2f whq[4];
    {
        const float* Wq = W + q * CATDIM + INDIM;
        #pragma unroll
        for (int p2 = 0; p2 < 4; ++p2)
            whq[p2] = mk2(INV2PI * Wq[q ^ (2 * p2)], INV2PI * Wq[q ^ (2 * p2 + 1)]);
    }
    const float bq = INV2PI * bs[q];

    // ---- bpermute addresses: lane holding wire w within own group ----
    int badr[8];
    {
        int base = lane & 0x34;                 // keep bits 2(g0), 4(g1), 5(el2)
        #pragma unroll
        for (int w = 0; w < 8; ++w)
            badr[w] = (base | ((w >> 2) & 1) | (((w >> 1) & 1) << 1) | ((w & 1) << 3)) << 2;
    }

    // ---- activation constants; kk*log2e folded into E-select ----
    const float kl = ((g == 2) ? 2.f : -1.f) * LOG2E;
    const float Aa = (g == 2) ? 1.f : 0.f;
    const float Bb = (g == 2) ? -1.f : 1.f;
    float sel[8];
    #pragma unroll
    for (int i = 0; i < 8; ++i) sel[i] = (q == i) ? kl : 0.f;

    // ---- state: h slots (slot o = h[q^o]); lane-local cell ----
    float s0h = 0.f, s1h = 0.f, s2h = 0.f, s3h = 0.f;
    float s4h = 0.f, s5h = 0.f, s6h = 0.f, s7h = 0.f;
    float c_own = 0.f, hv = 0.f;

    // ---- x chunk pointer + preload t=0 ----
    const float* xptr = x + (size_t)b * INDIM + 16 * q;
    float4 xv0 = *(const float4*)(xptr);
    float4 xv1 = *(const float4*)(xptr + 4);
    float4 xv2 = *(const float4*)(xptr + 8);
    float4 xv3 = *(const float4*)(xptr + 12);
    xptr += (size_t)BB * INDIM;

    for (int t = 0; t < TS; ++t) {
        // ---- 8 partial x-dots over own chunk ----
        v2f xc[8] = { mk2(xv0.x, xv0.y), mk2(xv0.z, xv0.w),
                      mk2(xv1.x, xv1.y), mk2(xv1.z, xv1.w),
                      mk2(xv2.x, xv2.y), mk2(xv2.z, xv2.w),
                      mk2(xv3.x, xv3.y), mk2(xv3.z, xv3.w) };
        float pt[8];
        #pragma unroll
        for (int j = 0; j < 8; ++j) {
            v2f acc = pk_mul(xc[0], xw[j][0]);
            acc = pk_fma(xc[1], xw[j][1], acc);
            acc = pk_fma(xc[2], xw[j][2], acc);
            acc = pk_fma(xc[3], xw[j][3], acc);
            acc = pk_fma(xc[4], xw[j][4], acc);
            acc = pk_fma(xc[5], xw[j][5], acc);
            acc = pk_fma(xc[6], xw[j][6], acc);
            acc = pk_fma(xc[7], xw[j][7], acc);
            pt[j] = acc.x + acc.y;
        }

        // prefetch next x chunk
        {
            float4 xn0 = *(const float4*)(xptr);
            float4 xn1 = *(const float4*)(xptr + 4);
            float4 xn2 = *(const float4*)(xptr + 8);
            float4 xn3 = *(const float4*)(xptr + 12);
            xptr += (t < TS - 2) ? (size_t)BB * INDIM : 0;
            xv0 = xn0; xv1 = xn1; xv2 = xn2; xv3 = xn3;
        }

        // ---- butterfly reduce (masks 1,2,8): lane ends with row q ----
        {
            float s, r;
            // stage 1: mask1, cond l0 -> row bit2
            s = l0 ? pt[0] : pt[4]; r = dpp_xor1(s); pt[0] = (l0 ? pt[4] : pt[0]) + r;
            s = l0 ? pt[1] : pt[5]; r = dpp_xor1(s); pt[1] = (l0 ? pt[5] : pt[1]) + r;
            s = l0 ? pt[2] : pt[6]; r = dpp_xor1(s); pt[2] = (l0 ? pt[6] : pt[2]) + r;
            s = l0 ? pt[3] : pt[7]; r = dpp_xor1(s); pt[3] = (l0 ? pt[7] : pt[3]) + r;
            // stage 2: mask2, cond l1 -> row bit1
            s = l1 ? pt[0] : pt[2]; r = dpp_xor2(s); pt[0] = (l1 ? pt[2] : pt[0]) + r;
            s = l1 ? pt[1] : pt[3]; r = dpp_xor2(s); pt[1] = (l1 ? pt[3] : pt[1]) + r;
            // stage 3: mask8, cond l3 -> row bit0
            s = l3 ? pt[0] : pt[1]; r = dpp_xor8(s); pt[0] = (l3 ? pt[1] : pt[0]) + r;
        }

        // ---- own-row angle: xdot + bias + h-dot ----
        v2f hacc = pk_fma(mk2(s0h, s1h), whq[0], mk2(pt[0] + bq, 0.f));
        hacc = pk_fma(mk2(s2h, s3h), whq[1], hacc);
        hacc = pk_fma(mk2(s4h, s5h), whq[2], hacc);
        hacc = pk_fma(mk2(s6h, s7h), whq[3], hacc);
        float ang = hacc.x + hacc.y;

        // ---- ONE sincos ----
        float sa_own = hw_sin(ang);
        float ca_own = hw_cos(ang);

        // ---- gather 8 wires in ABSOLUTE order via bpermute ----
        float saw[8], caw[8];
        #pragma unroll
        for (int w = 0; w < 8; ++w) {
            saw[w] = bperm(badr[w], sa_own);
            caw[w] = bperm(badr[w], ca_own);
        }

        // ---- serial transfer chain (verified R9-R13), own-E via sel-fma ----
        float kE = 0.f;
        float d0, d1, zr, zi;
        {
            float AmB = cp0c[0] * caw[0];
            d0 = Chw[0] * (1.f + AmB);
            d1 = -(Chw[0] * (1.f - AmB));
            zr = nSw[0] * (hsp0[0] * caw[0]);
            zi = nSw[0] * (-0.5f * saw[0]);
        }
        #pragma unroll
        for (int w = 1; w < 8; ++w) {
            float gr = hsp0[w] * caw[w];
            float gi = -0.5f * saw[w];
            float AmB = cp0c[w] * caw[w];
            float sum = d0 + d1, dif = d0 - d1;
            float p = gr * zr, qv = gi * zi;
            float Ew = fmaf(4.f, p, sum);
            kE = fmaf(sel[w - 1], Ew, kE);
            float ad = AmB * dif;
            float e1 = sum + ad, e3 = sum - ad;
            float e2 = p - qv, e4 = p + qv;
            float T0 = fmaf(4.f, e2, e1);
            float T1 = fmaf(4.f, e4, e3);
            float f1 = fmaf(gr, sum, zr);
            float f3 = fmaf(AmB, zi, gi * dif);
            d0 = Chw[w] * T0;
            d1 = -(Chw[w] * T1);
            zr = nSw[w] * f1;
            zi = nSw[w] * f3;
        }
        {
            float E7 = (d0 + d1) + 2.f * zr;
            kE = fmaf(sel[7], E7, kE);
        }

        // ---- own activation: act = (Aa*y + Bb) * rcp(y+1), y = 2^kE ----
        float y = hw_exp(kE);
        float a = fmaf(Aa, y, Bb) * hw_rcp(y + 1.f);

        // ---- gather 4 gates (swizzle masks 4,16,20 — verified R13) ----
        float b4 = swz4(a);
        float b16 = swz16(a);
        float b20 = swz20(a);
        bool g1b = (g & 2) != 0;
        bool g0b = (g & 1) != 0;
        float e0 = g1b ? b16 : a;
        float e1s = g1b ? b20 : b4;
        float e2s = g1b ? a : b16;
        float e3s = g1b ? b4 : b20;
        float fv = g0b ? e1s : e0;
        float iv = g0b ? e0 : e1s;
        float gv = g0b ? e3s : e2s;
        float ov = g0b ? e2s : e3s;

        // ---- lane-local LSTM ----
        c_own = fmaf(fv, c_own, iv * gv);
        float e2c = hw_exp(c_own * (2.f * LOG2E));
        hv = ov * ((e2c - 1.f) * hw_rcp(e2c + 1.f));

        if ((lane & 0x14) == 0)
            out[((size_t)t * BB + b) * NQ + q] = hv;

        // ---- h allgather butterfly: slot o = h[q^o] (masks 1->4, 2->2, 8->1) ----
        s0h = hv;
        s4h = dpp_xor1(s0h);
        s2h = dpp_xor2(s0h);
        s6h = dpp_xor2(s4h);
        s1h = dpp_xor8(s0h);
        s5h = dpp_xor8(s4h);
        s3h = dpp_xor8(s2h);
        s7h = dpp_xor8(s6h);
    }

    if ((lane & 0x14) == 0) {
        hst[b * NQ + q] = hv;
        cst[b * NQ + q] = c_own;
    }
}

extern "C" void kernel_launch(void* const* d_in, const int* in_sizes, int n_in,
                              void* d_out, int out_size, void* d_ws, size_t ws_size,
                              hipStream_t stream) {
    const float* x  = (const float*)d_in[0];
    const float* Wf = (const float*)d_in[1];
    const float* bf = (const float*)d_in[2];
    const float* Pf = (const float*)d_in[3];
    const float* Wi = (const float*)d_in[4];
    const float* bi = (const float*)d_in[5];
    const float* Pi = (const float*)d_in[6];
    const float* Wg = (const float*)d_in[7];
    const float* bg = (const float*)d_in[8];
    const float* Pg = (const float*)d_in[9];
    const float* Wo = (const float*)d_in[10];
    const float* bo = (const float*)d_in[11];
    const float* Po = (const float*)d_in[12];

    float* out = (float*)d_out;
    float* hst = out + (size_t)TS * BB * NQ;
    float* cst = hst + (size_t)BB * NQ;

    qlstm_f<<<BB / 2, 64, 0, stream>>>(x, Wf, bf, Pf, Wi, bi, Pi,
                                       Wg, bg, Pg, Wo, bo, Po,
                                       out, hst, cst);
}

// Round 15
// 231.282 us; speedup vs baseline: 1.5197x; 1.0220x over previous
//
#include <hip/hip_runtime.h>
#include <math.h>

#define TS 256
#define BB 1024
#define NQ 8
#define INDIM 128
#define CATDIM 136
#define INV2PI 0.15915494309189535f
#define LOG2E  1.4426950408889634f

typedef float v2f __attribute__((ext_vector_type(2)));

__device__ __forceinline__ float dpp_xor1(float v) {
    return __int_as_float(__builtin_amdgcn_mov_dpp(__float_as_int(v), 0xB1, 0xF, 0xF, true));
}
__device__ __forceinline__ float dpp_xor2(float v) {
    return __int_as_float(__builtin_amdgcn_mov_dpp(__float_as_int(v), 0x4E, 0xF, 0xF, true));
}
__device__ __forceinline__ float dpp_xor8(float v) {   // row_ror:8 within 16-lane row = lane^8
    return __int_as_float(__builtin_amdgcn_mov_dpp(__float_as_int(v), 0x128, 0xF, 0xF, true));
}
__device__ __forceinline__ float swz4(float v)  {      // ds_swizzle xor 4
    return __int_as_float(__builtin_amdgcn_ds_swizzle(__float_as_int(v), 0x101F));
}
__device__ __forceinline__ float swz16(float v) {      // ds_swizzle xor 16
    return __int_as_float(__builtin_amdgcn_ds_swizzle(__float_as_int(v), 0x401F));
}
__device__ __forceinline__ float swz20(float v) {      // ds_swizzle xor 20
    return __int_as_float(__builtin_amdgcn_ds_swizzle(__float_as_int(v), 0x501F));
}
__device__ __forceinline__ float hw_sin(float x) { float r; asm("v_sin_f32 %0, %1" : "=v"(r) : "v"(x)); return r; }
__device__ __forceinline__ float hw_cos(float x) { float r; asm("v_cos_f32 %0, %1" : "=v"(r) : "v"(x)); return r; }
__device__ __forceinline__ float hw_exp(float x) { float r; asm("v_exp_f32 %0, %1" : "=v"(r) : "v"(x)); return r; }
__device__ __forceinline__ float hw_rcp(float x) { float r; asm("v_rcp_f32 %0, %1" : "=v"(r) : "v"(x)); return r; }
__device__ __forceinline__ v2f mk2(float x, float y) { v2f r; r.x = x; r.y = y; return r; }
__device__ __forceinline__ v2f pk_mul(v2f a, v2f b) {
    v2f d; asm("v_pk_mul_f32 %0, %1, %2" : "=v"(d) : "v"(a), "v"(b)); return d;
}
__device__ __forceinline__ v2f pk_fma(v2f a, v2f b, v2f c) {
    v2f d; asm("v_pk_fma_f32 %0, %1, %2, %3" : "=v"(d) : "v"(a), "v"(b), "v"(c)); return d;
}

// ============ Single fused kernel: x-proj + TM recurrence ============
// lane = el2*32 + g1*16 + l3*8 + g0*4 + l1*2 + l0 ; q = 4*l0 + 2*l1 + l3.
// Per step: 8 partial x-dots over own 16-chunk, DPP butterfly-reduce -> own
// row's x-dot; + bias + own-row h-dot (h slots DPP-allgathered, order folded
// into weights); ONE sincos; wires (sa,ca) gathered in ABSOLUTE order via a
// sorted DPP allgather (7 dpp + 14 sel per value, ZERO DS); verified transfer
// chain; sel-fma own-E; activation; 3-swizzle gate gather; lane-local LSTM.
__launch_bounds__(64, 1)
__global__ void qlstm_f(const float* __restrict__ x,
    const float* __restrict__ Wf, const float* __restrict__ bf, const float* __restrict__ Pf,
    const float* __restrict__ Wi, const float* __restrict__ bi, const float* __restrict__ Pi,
    const float* __restrict__ Wg, const float* __restrict__ bg, const float* __restrict__ Pg,
    const float* __restrict__ Wo, const float* __restrict__ bo, const float* __restrict__ Po,
    float* __restrict__ out, float* __restrict__ hst, float* __restrict__ cst)
{
    const int lane = threadIdx.x;
    const int l0 = lane & 1, l1 = (lane >> 1) & 1, l3 = (lane >> 3) & 1;
    const int q = 4 * l0 + 2 * l1 + l3;
    const int g = ((lane >> 2) & 1) | ((lane >> 3) & 2);
    const int el2 = lane >> 5;
    const int b = blockIdx.x * 2 + el2;

    const float* W; const float* P; const float* bs;
    if (g == 0)      { W = Wf; P = Pf; bs = bf; }
    else if (g == 1) { W = Wi; P = Pi; bs = bi; }
    else if (g == 2) { W = Wg; P = Pg; bs = bg; }
    else             { W = Wo; P = Po; bs = bo; }

    // ---- per-wire trig constants ----
    float Chw[8], nSw[8], hsp0[8], cp0c[8];
    #pragma unroll
    for (int w = 0; w < 8; ++w) {
        float s1, c1, s0, c0;
        __sincosf(P[8 + w], &s1, &c1);
        __sincosf(P[w], &s0, &c0);
        Chw[w] = 0.5f * c1;
        nSw[w] = -s1;
        hsp0[w] = 0.5f * s0;
        cp0c[w] = c0;
    }

    // ---- x-weights: 8 rows x own 16-wide k-chunk (chunk = q), 1/2π-scaled ----
    v2f xw[8][8];
    #pragma unroll
    for (int j = 0; j < 8; ++j) {
        const float* Wj = W + j * CATDIM + 16 * q;
        #pragma unroll
        for (int p2 = 0; p2 < 4; ++p2) {
            float4 v = *(const float4*)(Wj + p2 * 4);
            xw[j][p2*2]   = mk2(INV2PI * v.x, INV2PI * v.y);
            xw[j][p2*2+1] = mk2(INV2PI * v.z, INV2PI * v.w);
        }
    }

    // ---- own-row h-weights, h-butterfly slot order folded (slot o = h[q^o]) ----
    v2f whq[4];
    {
        const float* Wq = W + q * CATDIM + INDIM;
        #pragma unroll
        for (int p2 = 0; p2 < 4; ++p2)
            whq[p2] = mk2(INV2PI * Wq[q ^ (2 * p2)], INV2PI * Wq[q ^ (2 * p2 + 1)]);
    }
    const float bq = INV2PI * bs[q];

    // ---- activation constants; kk*log2e folded into E-select ----
    const float kl = ((g == 2) ? 2.f : -1.f) * LOG2E;
    const float Aa = (g == 2) ? 1.f : 0.f;
    const float Bb = (g == 2) ? -1.f : 1.f;
    float sel[8];
    #pragma unroll
    for (int i = 0; i < 8; ++i) sel[i] = (q == i) ? kl : 0.f;

    // ---- state ----
    float s0h = 0.f, s1h = 0.f, s2h = 0.f, s3h = 0.f;
    float s4h = 0.f, s5h = 0.f, s6h = 0.f, s7h = 0.f;
    float c_own = 0.f, hv = 0.f;

    const float* xptr = x + (size_t)b * INDIM + 16 * q;
    float4 xv0 = *(const float4*)(xptr);
    float4 xv1 = *(const float4*)(xptr + 4);
    float4 xv2 = *(const float4*)(xptr + 8);
    float4 xv3 = *(const float4*)(xptr + 12);
    xptr += (size_t)BB * INDIM;

    for (int t = 0; t < TS; ++t) {
        // ---- 8 partial x-dots over own chunk ----
        v2f xc[8] = { mk2(xv0.x, xv0.y), mk2(xv0.z, xv0.w),
                      mk2(xv1.x, xv1.y), mk2(xv1.z, xv1.w),
                      mk2(xv2.x, xv2.y), mk2(xv2.z, xv2.w),
                      mk2(xv3.x, xv3.y), mk2(xv3.z, xv3.w) };
        float pt[8];
        #pragma unroll
        for (int j = 0; j < 8; ++j) {
            v2f acc = pk_mul(xc[0], xw[j][0]);
            acc = pk_fma(xc[1], xw[j][1], acc);
            acc = pk_fma(xc[2], xw[j][2], acc);
            acc = pk_fma(xc[3], xw[j][3], acc);
            acc = pk_fma(xc[4], xw[j][4], acc);
            acc = pk_fma(xc[5], xw[j][5], acc);
            acc = pk_fma(xc[6], xw[j][6], acc);
            acc = pk_fma(xc[7], xw[j][7], acc);
            pt[j] = acc.x + acc.y;
        }

        // prefetch next x chunk
        {
            float4 xn0 = *(const float4*)(xptr);
            float4 xn1 = *(const float4*)(xptr + 4);
            float4 xn2 = *(const float4*)(xptr + 8);
            float4 xn3 = *(const float4*)(xptr + 12);
            xptr += (t < TS - 2) ? (size_t)BB * INDIM : 0;
            xv0 = xn0; xv1 = xn1; xv2 = xn2; xv3 = xn3;
        }

        // ---- butterfly reduce (masks 1,2,8): lane ends with row q (verified R14) ----
        {
            float s, r;
            s = l0 ? pt[0] : pt[4]; r = dpp_xor1(s); pt[0] = (l0 ? pt[4] : pt[0]) + r;
            s = l0 ? pt[1] : pt[5]; r = dpp_xor1(s); pt[1] = (l0 ? pt[5] : pt[1]) + r;
            s = l0 ? pt[2] : pt[6]; r = dpp_xor1(s); pt[2] = (l0 ? pt[6] : pt[2]) + r;
            s = l0 ? pt[3] : pt[7]; r = dpp_xor1(s); pt[3] = (l0 ? pt[7] : pt[3]) + r;
            s = l1 ? pt[0] : pt[2]; r = dpp_xor2(s); pt[0] = (l1 ? pt[2] : pt[0]) + r;
            s = l1 ? pt[1] : pt[3]; r = dpp_xor2(s); pt[1] = (l1 ? pt[3] : pt[1]) + r;
            s = l3 ? pt[0] : pt[1]; r = dpp_xor8(s); pt[0] = (l3 ? pt[1] : pt[0]) + r;
        }

        // ---- own-row angle: xdot + bias + h-dot ----
        v2f hacc = pk_fma(mk2(s0h, s1h), whq[0], mk2(pt[0] + bq, 0.f));
        hacc = pk_fma(mk2(s2h, s3h), whq[1], hacc);
        hacc = pk_fma(mk2(s4h, s5h), whq[2], hacc);
        hacc = pk_fma(mk2(s6h, s7h), whq[3], hacc);
        float ang = hacc.x + hacc.y;

        // ---- ONE sincos ----
        float sa_own = hw_sin(ang);
        float ca_own = hw_cos(ang);

        // ---- SORTED DPP allgather: slots in ABSOLUTE wire order, zero DS ----
        // stage A (mask1, q-bit2): slots by a=q2
        float sa_0, sa_1, ca_0, ca_1;
        {
            float p = dpp_xor1(sa_own);
            sa_0 = l0 ? p : sa_own;  sa_1 = l0 ? sa_own : p;
            p = dpp_xor1(ca_own);
            ca_0 = l0 ? p : ca_own;  ca_1 = l0 ? ca_own : p;
        }
        // stage B (mask2, q-bit1): slots by (a,b)
        float sa00, sa01, sa10, sa11, ca00, ca01, ca10, ca11;
        {
            float p0 = dpp_xor2(sa_0), p1 = dpp_xor2(sa_1);
            sa00 = l1 ? p0 : sa_0;  sa01 = l1 ? sa_0 : p0;
            sa10 = l1 ? p1 : sa_1;  sa11 = l1 ? sa_1 : p1;
            p0 = dpp_xor2(ca_0); p1 = dpp_xor2(ca_1);
            ca00 = l1 ? p0 : ca_0;  ca01 = l1 ? ca_0 : p0;
            ca10 = l1 ? p1 : ca_1;  ca11 = l1 ? ca_1 : p1;
        }
        // stage C (mask8, q-bit0): final slots w = 4a+2b+c
        float saw[8], caw[8];
        {
            float p;
            p = dpp_xor8(sa00); saw[0] = l3 ? p : sa00; saw[1] = l3 ? sa00 : p;
            p = dpp_xor8(sa01); saw[2] = l3 ? p : sa01; saw[3] = l3 ? sa01 : p;
            p = dpp_xor8(sa10); saw[4] = l3 ? p : sa10; saw[5] = l3 ? sa10 : p;
            p = dpp_xor8(sa11); saw[6] = l3 ? p : sa11; saw[7] = l3 ? sa11 : p;
            p = dpp_xor8(ca00); caw[0] = l3 ? p : ca00; caw[1] = l3 ? ca00 : p;
            p = dpp_xor8(ca01); caw[2] = l3 ? p : ca01; caw[3] = l3 ? ca01 : p;
            p = dpp_xor8(ca10); caw[4] = l3 ? p : ca10; caw[5] = l3 ? ca10 : p;
            p = dpp_xor8(ca11); caw[6] = l3 ? p : ca11; caw[7] = l3 ? ca11 : p;
        }

        // ---- serial transfer chain (verified R9-R14), own-E via sel-fma ----
        float kE = 0.f;
        float d0, d1, zr, zi;
        {
            float AmB = cp0c[0] * caw[0];
            d0 = Chw[0] * (1.f + AmB);
            d1 = -(Chw[0] * (1.f - AmB));
            zr = nSw[0] * (hsp0[0] * caw[0]);
            zi = nSw[0] * (-0.5f * saw[0]);
        }
        #pragma unroll
        for (int w = 1; w < 8; ++w) {
            float gr = hsp0[w] * caw[w];
            float gi = -0.5f * saw[w];
            float AmB = cp0c[w] * caw[w];
            float sum = d0 + d1, dif = d0 - d1;
            float p = gr * zr, qv = gi * zi;
            float Ew = fmaf(4.f, p, sum);
            kE = fmaf(sel[w - 1], Ew, kE);
            float ad = AmB * dif;
            float e1 = sum + ad, e3 = sum - ad;
            float e2 = p - qv, e4 = p + qv;
            float T0 = fmaf(4.f, e2, e1);
            float T1 = fmaf(4.f, e4, e3);
            float f1 = fmaf(gr, sum, zr);
            float f3 = fmaf(AmB, zi, gi * dif);
            d0 = Chw[w] * T0;
            d1 = -(Chw[w] * T1);
            zr = nSw[w] * f1;
            zi = nSw[w] * f3;
        }
        {
            float E7 = (d0 + d1) + 2.f * zr;
            kE = fmaf(sel[7], E7, kE);
        }

        // ---- own activation ----
        float y = hw_exp(kE);
        float a = fmaf(Aa, y, Bb) * hw_rcp(y + 1.f);

        // ---- gather 4 gates (swizzle masks 4,16,20 — verified R13/R14) ----
        float b4 = swz4(a);
        float b16 = swz16(a);
        float b20 = swz20(a);
        bool g1b = (g & 2) != 0;
        bool g0b = (g & 1) != 0;
        float e0 = g1b ? b16 : a;
        float e1s = g1b ? b20 : b4;
        float e2s = g1b ? a : b16;
        float e3s = g1b ? b4 : b20;
        float fv = g0b ? e1s : e0;
        float iv = g0b ? e0 : e1s;
        float gv = g0b ? e3s : e2s;
        float ov = g0b ? e2s : e3s;

        // ---- lane-local LSTM ----
        c_own = fmaf(fv, c_own, iv * gv);
        float e2c = hw_exp(c_own * (2.f * LOG2E));
        hv = ov * ((e2c - 1.f) * hw_rcp(e2c + 1.f));

        if ((lane & 0x14) == 0)
            out[((size_t)t * BB + b) * NQ + q] = hv;

        // ---- h allgather butterfly (q^o order; weights pre-folded) ----
        s0h = hv;
        s4h = dpp_xor1(s0h);
        s2h = dpp_xor2(s0h);
        s6h = dpp_xor2(s4h);
        s1h = dpp_xor8(s0h);
        s5h = dpp_xor8(s4h);
        s3h = dpp_xor8(s2h);
        s7h = dpp_xor8(s6h);
    }

    if ((lane & 0x14) == 0) {
        hst[b * NQ + q] = hv;
        cst[b * NQ + q] = c_own;
    }
}

extern "C" void kernel_launch(void* const* d_in, const int* in_sizes, int n_in,
                              void* d_out, int out_size, void* d_ws, size_t ws_size,
                              hipStream_t stream) {
    const float* x  = (const float*)d_in[0];
    const float* Wf = (const float*)d_in[1];
    const float* bf = (const float*)d_in[2];
    const float* Pf = (const float*)d_in[3];
    const float* Wi = (const float*)d_in[4];
    const float* bi = (const float*)d_in[5];
    const float* Pi = (const float*)d_in[6];
    const float* Wg = (const float*)d_in[7];
    const float* bg = (const float*)d_in[8];
    const float* Pg = (const float*)d_in[9];
    const float* Wo = (const float*)d_in[10];
    const float* bo = (const float*)d_in[11];
    const float* Po = (const float*)d_in[12];

    float* out = (float*)d_out;
    float* hst = out + (size_t)TS * BB * NQ;
    float* cst = hst + (size_t)BB * NQ;

    qlstm_f<<<BB / 2, 64, 0, stream>>>(x, Wf, bf, Pf, Wi, bi, Pi,
                                       Wg, bg, Pg, Wo, bo, Po,
                                       out, hst, cst);
}